// Round 6
// baseline (139.241 us; speedup 1.0000x reference)
//
#include <hip/hip_runtime.h>
#include <hip/hip_bf16.h>

// ---------- types ----------
typedef __attribute__((ext_vector_type(8))) short bf16x8;   // 4 VGPR MFMA A/B frag
typedef __attribute__((ext_vector_type(4))) float f32x4;    // 4 VGPR MFMA C/D frag
typedef __attribute__((ext_vector_type(4))) unsigned int uint4v;
typedef __attribute__((address_space(1))) const unsigned int gu32;
typedef __attribute__((address_space(3))) unsigned int lu32;

__device__ __forceinline__ unsigned short f2bf(float f) {
    __hip_bfloat16 h = __float2bfloat16(f);   // RNE
    return __builtin_bit_cast(unsigned short, h);
}

template<int N> __device__ __forceinline__ void waitv() {
    asm volatile("s_waitcnt vmcnt(%0)" :: "i"(N) : "memory");
}
__device__ __forceinline__ void waitlgkm0() {
    asm volatile("s_waitcnt lgkmcnt(0)" ::: "memory");
}

// Problem constants: B=16, C=768, H=W=48 -> HW=2304, tokens/mod = 36864
#define BT 256            // tokens per block (=> 1KB contiguous channel-runs)
#define TPM 144           // tiles per modality = 36864/256
#define NCHUNK 24         // 768 / 32

// ---------- precompute: partial u/v sums (u = g.W1 col-sums, v = b.W1) ----------
__global__ void prep_partial(const float* __restrict__ w1, const float* __restrict__ lng,
                             const float* __restrict__ lnb,
                             float* __restrict__ upart, float* __restrict__ vpart)
{
    const int m   = blockIdx.x >> 3;
    const int seg = blockIdx.x & 7;
    const int d   = threadIdx.x;          // 192 threads
    const float* w1m = w1 + (size_t)m * 768 * 192;
    const float* gm  = lng + m * 768;
    const float* bm  = lnb + m * 768;
    const int c0 = seg * 96;
    float su = 0.f, sv = 0.f;
    for (int c = 0; c < 96; ++c) {
        float wv = w1m[(size_t)(c0 + c) * 192 + d];
        su += gm[c0 + c] * wv;
        sv += bm[c0 + c] * wv;
    }
    upart[(m * 8 + seg) * 192 + d] = su;
    vpart[(m * 8 + seg) * 192 + d] = sv;
}

__global__ void prep_combine(const float* __restrict__ upart, const float* __restrict__ vpart,
                             const float* __restrict__ b1,
                             float* __restrict__ u, float* __restrict__ vb)
{
    const int m = blockIdx.x;
    const int d = threadIdx.x;            // 192 threads
    float su = 0.f, sv = 0.f;
    for (int s = 0; s < 8; ++s) {
        su += upart[(m * 8 + s) * 192 + d];
        sv += vpart[(m * 8 + s) * 192 + d];
    }
    u[m * 192 + d]  = su;
    vb[m * 192 + d] = sv + b1[m * 192 + d];
}

// ---------- precompute: pack g*W1 as bf16 in MFMA B-fragment order ----------
// w1f[m][kk(24)][nf(12)][lane(64)][8]; B-frag lane l holds B[k=(l>>4)*8+j][n=l&15].
__global__ void prep_pack(const float* __restrict__ w1, const float* __restrict__ lng,
                          unsigned short* __restrict__ w1f)
{
    const int m  = blockIdx.x / 24;
    const int kk = blockIdx.x % 24;
    const int tid = threadIdx.x;          // 256 threads
    __shared__ float ws[32 * 192];
    const float* w1m = w1 + ((size_t)m * 768 + kk * 32) * 192;
    const float* gm  = lng + m * 768 + kk * 32;
    for (int i = tid; i < 6144; i += 256) {
        int cl = i / 192, d = i % 192;
        ws[i] = gm[cl] * w1m[(size_t)cl * 192 + d];
    }
    __syncthreads();
    unsigned short* outp = w1f + ((size_t)m * 24 + kk) * 6144;
    for (int i = tid; i < 6144; i += 256) {
        int nf   = i >> 9;
        int rem  = i & 511;
        int lane = rem >> 3;
        int j    = rem & 7;
        int cl   = ((lane >> 4) << 3) + j;
        int d    = (nf << 4) + (lane & 15);
        outp[i]  = f2bf(ws[cl * 192 + d]);
    }
}

// ---------- fused main kernel ----------
// 1024 thr (16 waves), 256 tokens/block. Wave w = (wi = w&3, wj = w>>2):
// tokens [wi*64,+64) x dims [wj*48,+48); acc 4x3 f32x4 = 48 VGPR.
//
// A-staging: per chunk (32 ch x 256 tok f32), wave w stages channels {2w,2w+1}
// via 2x global_load_lds dwordx4 -- each ONE fully-contiguous 1KB segment
// (lane l -> tokens 4l..4l+3). F[2][32][256] f32 queue, depth 2.
//
// Per chunk k (2 raw barriers, loads stay in flight across both):
//   waitv<W>    (own S(k) retired; exact table below)
//   bar1        (all stages of chunk k globally visible)
//   pack:       thread (tok=tid&255, cg=tid>>8) reads F[k&1][cg*8+j][tok] j=0..7
//               (2-lanes/bank, free), stats, bf16 pack, ONE b128 write to
//               At[k&1][tok][cg*8]  (row 80B: 5t mod 8 balanced -> conflict-free)
//   lgkm0; bar2 (At ready; all pack reads of F[k&1] done)
//   STAGE(k+2) -> F[k&1]   (safe: after bar2)
//   MFMA(k): At[k&1] x bf[k&1]  (compiler B-wait: drains S(<=k+1) only)
//   LOADB(k+1) -> bf[(k+1)&1]  (L2-hot, 1-chunk lead)
//
// vmcnt table (issue order: S0,S1,B0 | c0:S2,B1 | c1:S3,B2 | ... ck:S(k+2),B(k+1);
// stage=2 ops, B=3 ops; S skipped for k>=22, B skipped for k>=23; in-order retire):
//   top(0): younger-than-S0 = S1,B0 = 5
//   top(1..22): younger-than-S(k) = B(k-1),S(k+1),B(k) = 8
//   top(23): younger-than-S23 = B22,B23 = 6
__global__ __launch_bounds__(1024, 4)
void fused_main(const float* __restrict__ f0, const float* __restrict__ f1,
                const float* __restrict__ f2,
                const unsigned short* __restrict__ w1f,
                const float* __restrict__ u_g, const float* __restrict__ vb_g,
                const float* __restrict__ w2_g, const float* __restrict__ b2_g,
                float* __restrict__ out)
{
    const int bx   = blockIdx.x;
    const int mod  = bx / TPM;
    const int tile = bx % TPM;
    const float* feat = (mod == 0) ? f0 : ((mod == 1) ? f1 : f2);
    const int T0   = tile * BT;
    const int bimg = T0 / 2304;
    const int hw0  = T0 % 2304;               // 256 | 2304: no image crossing
    const float* fbase = feat + (size_t)bimg * 768 * 2304 + hw0;

    const int tid  = threadIdx.x;
    const int l    = tid & 63;
    const int w    = tid >> 6;     // wave 0..15
    const int wi   = w & 3;        // token quarter
    const int wj   = w >> 2;       // dim quarter (48 dims)
    const int tokp = tid & 255;    // pack role: token
    const int cg   = tid >> 8;     // pack role: 8-ch group
    const int col  = l & 15, lg = l >> 4;

    __shared__ float F[2][32][256];              // 64 KB staging queue
    __shared__ unsigned short At[2][256][40];    // 40 KB bf16, 80B rows
    __shared__ float Sred[4][256], Qred[4][256]; // 8 KB
    __shared__ float mu_s[256], rs_s[256];       // 2 KB
    __shared__ float red2[4][256];               // 4 KB

    const unsigned short* w1fm = w1f + (size_t)mod * 24 * 6144;

    f32x4 acc[4][3];
    #pragma unroll
    for (int a = 0; a < 4; ++a)
        #pragma unroll
        for (int b = 0; b < 3; ++b) acc[a][b] = (f32x4){0.f, 0.f, 0.f, 0.f};

    float sum = 0.f, ssq = 0.f;
    bf16x8 bfA[3], bfB[3];

    auto STAGE = [&](int kk, int buf) {
        #pragma unroll
        for (int c = 0; c < 2; ++c) {
            const float* src = fbase + (size_t)(kk * 32 + 2 * w + c) * 2304 + 4 * l;
            __builtin_amdgcn_global_load_lds((gu32*)src,
                                             (lu32*)&F[buf][2 * w + c][0], 16, 0, 0);
        }
        __builtin_amdgcn_sched_barrier(0);
    };
    auto LOADB = [&](int kk, bf16x8 (&bf)[3]) {
        const bf16x8* sB = reinterpret_cast<const bf16x8*>(w1fm + (size_t)kk * 6144);
        #pragma unroll
        for (int nf = 0; nf < 3; ++nf)
            bf[nf] = sB[(wj * 3 + nf) * 64 + l];     // 16B/lane, 1KB/instr, L2-hot
        __builtin_amdgcn_sched_barrier(0);
    };

#define STEPK(KK, WN, BUF, BFU, BFL, DO_S, DO_B)                               \
    {                                                                          \
        waitv<WN>();                                                           \
        __builtin_amdgcn_sched_barrier(0);                                     \
        __builtin_amdgcn_s_barrier();                                          \
        __builtin_amdgcn_sched_barrier(0);                                     \
        float xs[8];                                                           \
        _Pragma("unroll")                                                      \
        for (int jj = 0; jj < 8; ++jj) {                                       \
            xs[jj] = F[BUF][cg * 8 + jj][tokp];                                \
            sum += xs[jj]; ssq = fmaf(xs[jj], xs[jj], ssq);                    \
        }                                                                      \
        uint4v pk;                                                             \
        _Pragma("unroll")                                                      \
        for (int jj = 0; jj < 4; ++jj) {                                       \
            unsigned lo = (unsigned)f2bf(xs[2 * jj]);                          \
            unsigned hi = (unsigned)f2bf(xs[2 * jj + 1]);                      \
            pk[jj] = lo | (hi << 16);                                          \
        }                                                                      \
        *reinterpret_cast<uint4v*>(&At[BUF][tokp][cg * 8]) = pk;               \
        waitlgkm0();                                                           \
        __builtin_amdgcn_sched_barrier(0);                                     \
        __builtin_amdgcn_s_barrier();                                          \
        __builtin_amdgcn_sched_barrier(0);                                     \
        if (DO_S) STAGE((KK) + 2, BUF);                                        \
        bf16x8 af[4];                                                          \
        _Pragma("unroll")                                                      \
        for (int mf = 0; mf < 4; ++mf) {                                       \
            int t = wi * 64 + mf * 16 + col;                                   \
            af[mf] = *reinterpret_cast<const bf16x8*>(&At[BUF][t][lg * 8]);    \
        }                                                                      \
        _Pragma("unroll")                                                      \
        for (int mf = 0; mf < 4; ++mf)                                         \
            _Pragma("unroll")                                                  \
            for (int nf = 0; nf < 3; ++nf)                                     \
                acc[mf][nf] = __builtin_amdgcn_mfma_f32_16x16x32_bf16(         \
                                  af[mf], BFU[nf], acc[mf][nf], 0, 0, 0);      \
        if (DO_B) LOADB((KK) + 1, BFL);                                        \
    }

    // ---- prologue: S0, S1, B0 (order pinned for vmcnt table) ----
    STAGE(0, 0); STAGE(1, 1); LOADB(0, bfA);
    __builtin_amdgcn_sched_barrier(0);

    STEPK(0, 5, 0, bfA, bfB, true, true)
    #pragma unroll 1
    for (int m = 0; m < 11; ++m) {
        const int k1 = 2 * m + 1, k2 = 2 * m + 2;
        STEPK(k1, 8, 1, bfB, bfA, true, true)             // k1 = 1..21
        STEPK(k2, 8, 0, bfA, bfB, (k2 < 22), (k2 < 23))   // k2 = 2..22
    }
    STEPK(23, 6, 1, bfB, bfA, false, false)
#undef STEPK

    // ---- LayerNorm stats (per token over all 768 ch) ----
    Sred[cg][tokp] = sum;
    Qred[cg][tokp] = ssq;
    __syncthreads();
    if (tid < 256) {
        float S = Sred[0][tid] + Sred[1][tid] + Sred[2][tid] + Sred[3][tid];
        float Q = Qred[0][tid] + Qred[1][tid] + Qred[2][tid] + Qred[3][tid];
        float mu = S * (1.f / 768.f);
        float var = Q * (1.f / 768.f) - mu * mu;
        mu_s[tid] = mu;
        rs_s[tid] = rsqrtf(var + 1e-5f);
    }
    __syncthreads();

    // ---- epilogue: affine LN fix + GELU + dot(w2) + sigmoid ----
    const float* um  = u_g  + mod * 192;
    const float* vbm = vb_g + mod * 192;
    const float* w2m = w2_g + mod * 192;
    float uf[3], vbf[3], w2f[3];
    #pragma unroll
    for (int nf = 0; nf < 3; ++nf) {
        int d = wj * 48 + nf * 16 + col;
        uf[nf] = um[d]; vbf[nf] = vbm[d]; w2f[nf] = w2m[d];
    }
    float ps[4][4];
    #pragma unroll
    for (int mf = 0; mf < 4; ++mf) {
        #pragma unroll
        for (int r = 0; r < 4; ++r) {
            int t = wi * 64 + mf * 16 + lg * 4 + r;   // C/D: row=(lane>>4)*4+reg
            float mu = mu_s[t], rs = rs_s[t];
            float pp = 0.f;
            #pragma unroll
            for (int nf = 0; nf < 3; ++nf) {
                float x = rs * (acc[mf][nf][r] - mu * uf[nf]) + vbf[nf];
                float h = 0.5f * x * (1.f + erff(x * 0.70710678118f));  // exact GELU
                pp += h * w2f[nf];
            }
            ps[mf][r] = pp;
        }
    }
    #pragma unroll
    for (int m = 1; m < 16; m <<= 1)
        #pragma unroll
        for (int mf = 0; mf < 4; ++mf)
            #pragma unroll
            for (int r = 0; r < 4; ++r)
                ps[mf][r] += __shfl_xor(ps[mf][r], m, 64);
    if (col == 0) {
        #pragma unroll
        for (int mf = 0; mf < 4; ++mf)
            #pragma unroll
            for (int r = 0; r < 4; ++r)
                red2[wj][wi * 64 + mf * 16 + lg * 4 + r] = ps[mf][r];
    }
    __syncthreads();
    if (tid < 256) {
        float logit = red2[0][tid] + red2[1][tid] + red2[2][tid] + red2[3][tid] + b2_g[mod];
        out[(size_t)mod * 36864 + T0 + tid] = 1.f / (1.f + expf(-logit));
    }
}

// ---------- launch ----------
extern "C" void kernel_launch(void* const* d_in, const int* in_sizes, int n_in,
                              void* d_out, int out_size, void* d_ws, size_t ws_size,
                              hipStream_t stream)
{
    const float* f0  = (const float*)d_in[0];
    const float* f1  = (const float*)d_in[1];
    const float* f2  = (const float*)d_in[2];
    const float* lng = (const float*)d_in[3];
    const float* lnb = (const float*)d_in[4];
    const float* w1  = (const float*)d_in[5];
    const float* b1  = (const float*)d_in[6];
    const float* w2  = (const float*)d_in[7];
    const float* b2  = (const float*)d_in[8];
    float* out = (float*)d_out;

    char* ws = (char*)d_ws;
    unsigned short* w1f = (unsigned short*)ws;          // 884736 B
    float* u     = (float*)(ws + 884736);               // 2304 B
    float* vb    = (float*)(ws + 887040);               // 2304 B
    float* upart = (float*)(ws + 889344);               // 18432 B
    float* vpart = (float*)(ws + 907776);               // 18432 B

    prep_partial<<<dim3(24), dim3(192), 0, stream>>>(w1, lng, lnb, upart, vpart);
    prep_combine<<<dim3(3),  dim3(192), 0, stream>>>(upart, vpart, b1, u, vb);
    prep_pack   <<<dim3(72), dim3(256), 0, stream>>>(w1, lng, w1f);
    fused_main  <<<dim3(3 * TPM), dim3(1024), 0, stream>>>(f0, f1, f2, w1f, u, vb, w2, b2, out);
}